// Round 2
// 15137.250 us; speedup vs baseline: 1.4596x; 1.4596x over previous
//
#include <hip/hip_runtime.h>
#include <hip/hip_bf16.h>
#include <math.h>

// Problem constants
constexpr int Bc = 4, Sc = 1024, Dc = 1024, Hc = 16, Lc = 4, Fc = 4096, Vc = 32000;
constexpr int DKc = 64;
constexpr int Mc = Bc * Sc;          // 4096 tokens
constexpr float EPSc = 1e-5f;

// ---------------------------------------------------------------------------
// Embedding + positional encoding: h[m,d] = emb[x[m],d]*32 + PE(s,d)
// ---------------------------------------------------------------------------
__global__ __launch_bounds__(256) void embed_k(const int* __restrict__ x,
                                               const float* __restrict__ emb,
                                               float* __restrict__ h) {
    int m = blockIdx.x;            // token index
    int s = m & (Sc - 1);          // position within sequence
    int tid = threadIdx.x;
    int d0 = tid * 4;
    int tok = x[m];
    float4 e = *(const float4*)&emb[(size_t)tok * Dc + d0];
    // pair indices p0, p0+1 ;  div[p] = exp(-ln(10000) * p / 512)
    const float c = -9.210340371976184f / 512.0f;   // -ln(10000)/(D/2)
    float p0 = (float)(tid * 2);
    float fs = (float)s;
    float ang0 = fs * __expf(c * p0);
    float ang1 = fs * __expf(c * (p0 + 1.0f));
    float4 o;
    o.x = e.x * 32.0f + sinf(ang0);
    o.y = e.y * 32.0f + cosf(ang0);
    o.z = e.z * 32.0f + sinf(ang1);
    o.w = e.w * 32.0f + cosf(ang1);
    *(float4*)&h[(size_t)m * Dc + d0] = o;
}

// ---------------------------------------------------------------------------
// Tiled fp32 GEMM: C[M,N] = A[M,K] @ B[K,N]  (+ epilogues)
// MODE 0: plain   MODE 1: +bias   MODE 2: +bias, exact GELU
// MODE 3: QKV scatter -> out[b, head, s, dk]  (no bias)
// BM=BN=64, BK=16, 256 threads, 4x4 micro-tile per thread
// LDS tiles padded to [16][68]: As scalar writes drop 4-way -> 2-way conflict
// (2-way is free on gfx950), float4 alignment preserved (68*4B = 272B, 16B-mult).
// ---------------------------------------------------------------------------
__device__ __forceinline__ float gelu_exact(float v) {
    return 0.5f * v * (1.0f + erff(v * 0.70710678118654752f));
}

template<int MODE>
__global__ __launch_bounds__(256) void gemm_k(const float* __restrict__ A,
                                              const float* __restrict__ Bm,
                                              const float* __restrict__ bias,
                                              float* __restrict__ C,
                                              int Kd, int Nd) {
    __shared__ float As[16][68];   // [k][m] (transposed), padded
    __shared__ float Bs[16][68];   // [k][n], padded
    int tid = threadIdx.x;
    int bm = blockIdx.y * 64;
    int bn = blockIdx.x * 64;
    int tx = tid & 15;             // col group
    int ty = tid >> 4;             // row group
    float acc[4][4] = {};

    int arow = tid >> 2;           // 0..63
    int akq  = tid & 3;            // k-quad
    int bkrow = tid >> 4;          // 0..15
    int bn4   = tid & 15;          // col-quad

    const float* Aptr = A + (size_t)(bm + arow) * Kd + akq * 4;
    const float* Bptr = Bm + (size_t)bkrow * Nd + bn + bn4 * 4;

    for (int k0 = 0; k0 < Kd; k0 += 16) {
        float4 av = *(const float4*)(Aptr + k0);
        float4 bv = *(const float4*)(Bptr + (size_t)k0 * Nd);
        As[akq * 4 + 0][arow] = av.x;
        As[akq * 4 + 1][arow] = av.y;
        As[akq * 4 + 2][arow] = av.z;
        As[akq * 4 + 3][arow] = av.w;
        *(float4*)&Bs[bkrow][bn4 * 4] = bv;
        __syncthreads();
#pragma unroll
        for (int kk = 0; kk < 16; kk++) {
            float4 a4 = *(const float4*)&As[kk][ty * 4];
            float4 b4 = *(const float4*)&Bs[kk][tx * 4];
            acc[0][0] += a4.x * b4.x; acc[0][1] += a4.x * b4.y;
            acc[0][2] += a4.x * b4.z; acc[0][3] += a4.x * b4.w;
            acc[1][0] += a4.y * b4.x; acc[1][1] += a4.y * b4.y;
            acc[1][2] += a4.y * b4.z; acc[1][3] += a4.y * b4.w;
            acc[2][0] += a4.z * b4.x; acc[2][1] += a4.z * b4.y;
            acc[2][2] += a4.z * b4.z; acc[2][3] += a4.z * b4.w;
            acc[3][0] += a4.w * b4.x; acc[3][1] += a4.w * b4.y;
            acc[3][2] += a4.w * b4.z; acc[3][3] += a4.w * b4.w;
        }
        __syncthreads();
    }

#pragma unroll
    for (int i = 0; i < 4; i++) {
        int gm = bm + ty * 4 + i;
#pragma unroll
        for (int j = 0; j < 4; j++) {
            int gn = bn + tx * 4 + j;
            float v = acc[i][j];
            if (MODE == 1 || MODE == 2) v += bias[gn];
            if (MODE == 2) v = gelu_exact(v);
            if (MODE == 3) {
                int b = gm >> 10, s = gm & 1023;
                int hh = gn >> 6, dk = gn & 63;
                C[(((size_t)(b * Hc + hh) * Sc) + s) * DKc + dk] = v;
            } else {
                C[(size_t)gm * Nd + gn] = v;
            }
        }
    }
}

// ---------------------------------------------------------------------------
// Flash-style attention, fp32. One wave (64 threads) per 64-query tile.
// thread <-> query: Q row (64 f32) and output acc (64 f32) live in registers,
// online-softmax state (m, l) is thread-local -> no cross-lane reductions.
// K/V staged in LDS in 32-key tiles (coalesced float4 loads); inner-loop LDS
// reads are same-address broadcasts (conflict-free). Causal: block qt only
// visits tiles 0..(qt*2+1).
// ---------------------------------------------------------------------------
constexpr int QT = 64;   // queries per block (= wave size)
constexpr int KT = 32;   // keys per LDS tile

__global__ __launch_bounds__(64) void fattn_k(const float* __restrict__ Q,
                                              const float* __restrict__ K,
                                              const float* __restrict__ V,
                                              const int* __restrict__ x,
                                              float* __restrict__ ctx) {
    int qt = blockIdx.x;
    int bh = blockIdx.y;
    int b = bh >> 4;
    int hh = bh & 15;
    int tid = threadIdx.x;           // 0..63
    int q = qt * QT + tid;           // this thread's query row

    __shared__ float Ks[KT][64];
    __shared__ float Vs[KT][64];
    __shared__ int   xs[KT];

    const float* Kb = K + (size_t)bh * Sc * DKc;
    const float* Vb = V + (size_t)bh * Sc * DKc;

    // Q row -> registers
    float4 q4[16];
    const float* qp = Q + ((size_t)bh * Sc + q) * DKc;
#pragma unroll
    for (int i = 0; i < 16; i++) q4[i] = *(const float4*)(qp + 4 * i);

    float4 acc[16];
#pragma unroll
    for (int i = 0; i < 16; i++) acc[i] = make_float4(0.f, 0.f, 0.f, 0.f);
    float m = -INFINITY, l = 0.0f;

    int ktiles = (qt * QT + QT) / KT;         // tiles covering keys 0..qmax
    for (int t = 0; t < ktiles; t++) {
        int k0 = t * KT;
        __syncthreads();                       // protect LDS from prev iter
        // stage K,V tile: KT*16 float4 each, fully coalesced
        for (int f = tid; f < KT * 16; f += 64) {
            int kr = f >> 4;
            int dc = (f & 15) * 4;
            *(float4*)&Ks[kr][dc] = *(const float4*)&Kb[(size_t)(k0 + kr) * DKc + dc];
            *(float4*)&Vs[kr][dc] = *(const float4*)&Vb[(size_t)(k0 + kr) * DKc + dc];
        }
        if (tid < KT) xs[tid] = x[b * Sc + k0 + tid];
        __syncthreads();

        // scores for KT keys
        float sc[KT];
#pragma unroll
        for (int k = 0; k < KT; k++) {
            float4 s4 = make_float4(0.f, 0.f, 0.f, 0.f);
#pragma unroll
            for (int i = 0; i < 16; i++) {
                float4 kv = *(const float4*)&Ks[k][4 * i];
                s4.x += q4[i].x * kv.x;
                s4.y += q4[i].y * kv.y;
                s4.z += q4[i].z * kv.z;
                s4.w += q4[i].w * kv.w;
            }
            float s = (s4.x + s4.y) + (s4.z + s4.w);
            bool valid = ((k0 + k) <= q) && (xs[k] != 0);
            sc[k] = valid ? s * 0.125f : -INFINITY;
        }

        // online softmax rescale (branchless)
        float tm = sc[0];
#pragma unroll
        for (int k = 1; k < KT; k++) tm = fmaxf(tm, sc[k]);
        float mnew = fmaxf(m, tm);
        float corr = __expf(m - mnew);   // m=-inf first tile -> corr=0
        l *= corr;
#pragma unroll
        for (int i = 0; i < 16; i++) {
            acc[i].x *= corr; acc[i].y *= corr;
            acc[i].z *= corr; acc[i].w *= corr;
        }
        m = mnew;

        // P @ V accumulate
#pragma unroll
        for (int k = 0; k < KT; k++) {
            float p = __expf(sc[k] - m);
            l += p;
#pragma unroll
            for (int i = 0; i < 16; i++) {
                float4 vv = *(const float4*)&Vs[k][4 * i];
                acc[i].x += p * vv.x;
                acc[i].y += p * vv.y;
                acc[i].z += p * vv.z;
                acc[i].w += p * vv.w;
            }
        }
    }

    float inv = 1.0f / l;
    float* op = ctx + ((size_t)b * Sc + q) * Dc + hh * 64;
#pragma unroll
    for (int i = 0; i < 16; i++) {
        float4 o;
        o.x = acc[i].x * inv; o.y = acc[i].y * inv;
        o.z = acc[i].z * inv; o.w = acc[i].w * inv;
        *(float4*)(op + 4 * i) = o;
    }
}

// ---------------------------------------------------------------------------
// Residual add + LayerNorm over D=1024. One block per row (in-place on h ok).
// ---------------------------------------------------------------------------
__global__ __launch_bounds__(256) void lnadd_k(const float* x, const float* r,
                                               const float* __restrict__ g,
                                               const float* __restrict__ bb,
                                               float* out) {
    int row = blockIdx.x, tid = threadIdx.x;
    int lane = tid & 63, wid = tid >> 6;
    __shared__ float red[8];
    size_t base = (size_t)row * Dc + tid * 4;
    float4 xv = *(const float4*)(x + base);
    float4 rv = *(const float4*)(r + base);
    float v0 = xv.x + rv.x, v1 = xv.y + rv.y, v2 = xv.z + rv.z, v3 = xv.w + rv.w;
    float sum = v0 + v1 + v2 + v3;
    float sq = v0 * v0 + v1 * v1 + v2 * v2 + v3 * v3;
    for (int off = 32; off; off >>= 1) {
        sum += __shfl_down(sum, off);
        sq  += __shfl_down(sq, off);
    }
    if (lane == 0) { red[wid] = sum; red[4 + wid] = sq; }
    __syncthreads();
    if (tid == 0) {
        red[0] = red[0] + red[1] + red[2] + red[3];
        red[4] = red[4] + red[5] + red[6] + red[7];
    }
    __syncthreads();
    float mu = red[0] * (1.0f / Dc);
    float var = red[4] * (1.0f / Dc) - mu * mu;
    float rs = rsqrtf(var + EPSc);
    int d = tid * 4;
    float4 gv = *(const float4*)(g + d);
    float4 bv = *(const float4*)(bb + d);
    float4 o;
    o.x = (v0 - mu) * rs * gv.x + bv.x;
    o.y = (v1 - mu) * rs * gv.y + bv.y;
    o.z = (v2 - mu) * rs * gv.z + bv.z;
    o.w = (v3 - mu) * rs * gv.w + bv.w;
    *(float4*)(out + base) = o;
}

// ---------------------------------------------------------------------------
extern "C" void kernel_launch(void* const* d_in, const int* in_sizes, int n_in,
                              void* d_out, int out_size, void* d_ws, size_t ws_size,
                              hipStream_t stream) {
    const int*   x     = (const int*)d_in[0];
    const float* emb   = (const float*)d_in[1];
    const float* Wq    = (const float*)d_in[2];
    const float* Wk    = (const float*)d_in[3];
    const float* Wv    = (const float*)d_in[4];
    const float* Wo    = (const float*)d_in[5];
    const float* bo    = (const float*)d_in[6];
    const float* ln1g  = (const float*)d_in[7];
    const float* ln1b  = (const float*)d_in[8];
    const float* ln2g  = (const float*)d_in[9];
    const float* ln2b  = (const float*)d_in[10];
    const float* W1    = (const float*)d_in[11];
    const float* b1    = (const float*)d_in[12];
    const float* W2    = (const float*)d_in[13];
    const float* b2    = (const float*)d_in[14];
    const float* Wout  = (const float*)d_in[15];
    const float* bout  = (const float*)d_in[16];
    float* out = (float*)d_out;
    float* ws = (float*)d_ws;

    const size_t MD = (size_t)Mc * Dc;   // 4M floats
    float* h    = ws;
    float* q    = ws + 1 * MD;
    float* k    = ws + 2 * MD;
    float* v    = ws + 3 * MD;
    float* ctx  = ws + 4 * MD;
    float* tmp  = ws + 5 * MD;           // attn_out / ff2
    float* ff1  = q;                     // reuses q..ctx span (16M floats = M*F)

    embed_k<<<Mc, 256, 0, stream>>>(x, emb, h);

    dim3 gridDD(Dc / 64, Mc / 64);       // N=1024 tiles
    dim3 gridDF(Fc / 64, Mc / 64);       // N=4096 tiles
    dim3 gridOut(Vc / 64, Mc / 64);      // N=32000 tiles

    for (int l = 0; l < Lc; l++) {
        const float* wq = Wq + (size_t)l * Dc * Dc;
        const float* wk = Wk + (size_t)l * Dc * Dc;
        const float* wv = Wv + (size_t)l * Dc * Dc;
        const float* wo = Wo + (size_t)l * Dc * Dc;
        const float* w1 = W1 + (size_t)l * Dc * Fc;
        const float* w2 = W2 + (size_t)l * Fc * Dc;

        gemm_k<3><<<gridDD, 256, 0, stream>>>(h, wq, nullptr, q, Dc, Dc);
        gemm_k<3><<<gridDD, 256, 0, stream>>>(h, wk, nullptr, k, Dc, Dc);
        gemm_k<3><<<gridDD, 256, 0, stream>>>(h, wv, nullptr, v, Dc, Dc);

        fattn_k<<<dim3(Sc / QT, Bc * Hc), QT, 0, stream>>>(q, k, v, x, ctx);

        gemm_k<1><<<gridDD, 256, 0, stream>>>(ctx, wo, bo + l * Dc, tmp, Dc, Dc);
        lnadd_k<<<Mc, 256, 0, stream>>>(h, tmp, ln1g + l * Dc, ln1b + l * Dc, h);

        gemm_k<2><<<gridDF, 256, 0, stream>>>(h, w1, b1 + l * Fc, ff1, Dc, Fc);
        gemm_k<1><<<gridDD, 256, 0, stream>>>(ff1, w2, b2 + l * Dc, tmp, Fc, Dc);
        lnadd_k<<<Mc, 256, 0, stream>>>(h, tmp, ln2g + l * Dc, ln2b + l * Dc, h);
    }

    gemm_k<1><<<gridOut, 256, 0, stream>>>(h, Wout, bout, out, Dc, Vc);
}

// Round 5
// 9336.481 us; speedup vs baseline: 2.3664x; 1.6213x over previous
//
#include <hip/hip_runtime.h>
#include <hip/hip_bf16.h>
#include <math.h>

// Problem constants
constexpr int Bc = 4, Sc = 1024, Dc = 1024, Hc = 16, Lc = 4, Fc = 4096, Vc = 32000;
constexpr int DKc = 64;
constexpr int Mc = Bc * Sc;          // 4096 tokens
constexpr float EPSc = 1e-5f;

typedef __attribute__((ext_vector_type(8))) short short8v;   // 8 bf16 (4 VGPR)
typedef __attribute__((ext_vector_type(4))) float f32x4;     // MFMA acc

// ---------------------------------------------------------------------------
// bf16 split: f = hi + lo, each RNE bf16. 3-product MFMA gives ~fp32 accuracy.
// ---------------------------------------------------------------------------
__device__ __forceinline__ ushort bf16_rne(float f) {
    uint u = __float_as_uint(f);
    return (ushort)((u + 0x7fffu + ((u >> 16) & 1u)) >> 16);
}
__device__ __forceinline__ void split2(float f, ushort& h, ushort& l) {
    ushort hh = bf16_rne(f);
    float hf = __uint_as_float(((uint)hh) << 16);
    h = hh;
    l = bf16_rne(f - hf);
}

// ---------------------------------------------------------------------------
// Embedding + positional encoding: h[m,d] = emb[x[m],d]*32 + PE(s,d)
// ---------------------------------------------------------------------------
__global__ __launch_bounds__(256) void embed_k(const int* __restrict__ x,
                                               const float* __restrict__ emb,
                                               float* __restrict__ h) {
    int m = blockIdx.x;
    int s = m & (Sc - 1);
    int tid = threadIdx.x;
    int d0 = tid * 4;
    int tok = x[m];
    float4 e = *(const float4*)&emb[(size_t)tok * Dc + d0];
    const float c = -9.210340371976184f / 512.0f;   // -ln(10000)/(D/2)
    float p0 = (float)(tid * 2);
    float fs = (float)s;
    float ang0 = fs * __expf(c * p0);
    float ang1 = fs * __expf(c * (p0 + 1.0f));
    float4 o;
    o.x = e.x * 32.0f + sinf(ang0);
    o.y = e.y * 32.0f + cosf(ang0);
    o.z = e.z * 32.0f + sinf(ang1);
    o.w = e.w * 32.0f + cosf(ang1);
    *(float4*)&h[(size_t)m * Dc + d0] = o;
}

__device__ __forceinline__ float gelu_exact(float v) {
    return 0.5f * v * (1.0f + erff(v * 0.70710678118654752f));
}

// ---------------------------------------------------------------------------
// Weight pre-conversion: W[K][N] fp32 -> hi[N][K], lo[N][K] bf16 (transposed
// so MFMA B-fragments read 8 contiguous k). 64x64 tile per block via LDS.
// ---------------------------------------------------------------------------
__global__ __launch_bounds__(256) void wconv_k(const float* __restrict__ W,
                                               ushort* __restrict__ hi,
                                               ushort* __restrict__ lo,
                                               int Kd, int Nd) {
    __shared__ float T[64][65];
    int nt = blockIdx.x * 64, kt = blockIdx.y * 64;
    int tid = threadIdx.x;
    int r16 = tid >> 4, c4 = (tid & 15) * 4;
#pragma unroll
    for (int p = 0; p < 4; p++) {
        int k = r16 + p * 16;
        float4 v = *(const float4*)&W[(size_t)(kt + k) * Nd + nt + c4];
        T[k][c4 + 0] = v.x; T[k][c4 + 1] = v.y;
        T[k][c4 + 2] = v.z; T[k][c4 + 3] = v.w;
    }
    __syncthreads();
#pragma unroll
    for (int p = 0; p < 4; p++) {
        int n = r16 + p * 16;
        ushort4 oh, ol;
        ushort hv, lv;
        split2(T[c4 + 0][n], hv, lv); oh.x = hv; ol.x = lv;
        split2(T[c4 + 1][n], hv, lv); oh.y = hv; ol.y = lv;
        split2(T[c4 + 2][n], hv, lv); oh.z = hv; ol.z = lv;
        split2(T[c4 + 3][n], hv, lv); oh.w = hv; ol.w = lv;
        size_t o = (size_t)(nt + n) * Kd + kt + c4;
        *(ushort4*)&hi[o] = oh;
        *(ushort4*)&lo[o] = ol;
    }
}

// ---------------------------------------------------------------------------
// MFMA GEMM with split-bf16 (3 products: hi*hi + hi*lo + lo*hi ~= fp32).
// C[M,N] = A[M,K](fp32) @ W (pre-converted bf16 hi/lo in [n][k] layout).
// BM=BN=128, BK=32, 256 threads = 4 waves, each wave a 64x64 quadrant of
// 4x4 mfma_f32_16x16x32_bf16 fragments. A converted to hi/lo during staging.
// LDS rows padded to 40 ushorts (80B stride, 16B-aligned): frag ds_read_b128
// is 2-way bank aliased (free on gfx950).
// MODE 0: plain  1: +bias  2: +bias+GELU  3: QKV scatter [b,h,s,dk]
// ---------------------------------------------------------------------------
template<int MODE>
__global__ __launch_bounds__(256) void mgemm_k(const float* __restrict__ A,
                                               const ushort* __restrict__ Bh_g,
                                               const ushort* __restrict__ Bl_g,
                                               const float* __restrict__ bias,
                                               float* __restrict__ C,
                                               int Kd, int Nd) {
    __shared__ ushort Ah[128][40], Al[128][40], Bh[128][40], Bl[128][40];
    int tid = threadIdx.x;
    int bm = blockIdx.y * 128, bn = blockIdx.x * 128;
    int lane = tid & 63, w = tid >> 6;
    int wr = w >> 1, wc = w & 1;
    int l15 = lane & 15, loct = lane >> 4;

    int sr = tid >> 1, sh = tid & 1;   // staging: row 0..127, k-half 0/1
    const float*  Ap  = A    + (size_t)(bm + sr) * Kd + sh * 16;
    const ushort* Bhp = Bh_g + (size_t)(bn + sr) * Kd + sh * 16;
    const ushort* Blp = Bl_g + (size_t)(bn + sr) * Kd + sh * 16;

    f32x4 acc[4][4];
#pragma unroll
    for (int i = 0; i < 4; i++)
#pragma unroll
        for (int j = 0; j < 4; j++) acc[i][j] = (f32x4){0.f, 0.f, 0.f, 0.f};

    for (int k0 = 0; k0 < Kd; k0 += 32) {
        float4 a0 = *(const float4*)(Ap + k0 + 0);
        float4 a1 = *(const float4*)(Ap + k0 + 4);
        float4 a2 = *(const float4*)(Ap + k0 + 8);
        float4 a3 = *(const float4*)(Ap + k0 + 12);
        uint4 b0 = *(const uint4*)(Bhp + k0);
        uint4 b1 = *(const uint4*)(Bhp + k0 + 8);
        uint4 b2 = *(const uint4*)(Blp + k0);
        uint4 b3 = *(const uint4*)(Blp + k0 + 8);

        union { ushort u[16]; short8v v[2]; } hA, lA;
        float fa[16] = {a0.x, a0.y, a0.z, a0.w, a1.x, a1.y, a1.z, a1.w,
                        a2.x, a2.y, a2.z, a2.w, a3.x, a3.y, a3.z, a3.w};
#pragma unroll
        for (int i = 0; i < 16; i++) {
            ushort hv, lv;
            split2(fa[i], hv, lv);
            hA.u[i] = hv; lA.u[i] = lv;
        }

        __syncthreads();   // protect previous iteration's fragment reads
        *(short8v*)&Ah[sr][sh * 16 + 0] = hA.v[0];
        *(short8v*)&Ah[sr][sh * 16 + 8] = hA.v[1];
        *(short8v*)&Al[sr][sh * 16 + 0] = lA.v[0];
        *(short8v*)&Al[sr][sh * 16 + 8] = lA.v[1];
        *(uint4*)&Bh[sr][sh * 16 + 0] = b0;
        *(uint4*)&Bh[sr][sh * 16 + 8] = b1;
        *(uint4*)&Bl[sr][sh * 16 + 0] = b2;
        *(uint4*)&Bl[sr][sh * 16 + 8] = b3;
        __syncthreads();

        short8v ah[4], al[4], bh[4], bl[4];
#pragma unroll
        for (int m = 0; m < 4; m++) {
            int r = wr * 64 + m * 16 + l15;
            ah[m] = *(const short8v*)&Ah[r][loct * 8];
            al[m] = *(const short8v*)&Al[r][loct * 8];
        }
#pragma unroll
        for (int n = 0; n < 4; n++) {
            int ccol = wc * 64 + n * 16 + l15;
            bh[n] = *(const short8v*)&Bh[ccol][loct * 8];
            bl[n] = *(const short8v*)&Bl[ccol][loct * 8];
        }
#pragma unroll
        for (int m = 0; m < 4; m++)
#pragma unroll
            for (int n = 0; n < 4; n++) {
                acc[m][n] = __builtin_amdgcn_mfma_f32_16x16x32_bf16(ah[m], bh[n], acc[m][n], 0, 0, 0);
                acc[m][n] = __builtin_amdgcn_mfma_f32_16x16x32_bf16(ah[m], bl[n], acc[m][n], 0, 0, 0);
                acc[m][n] = __builtin_amdgcn_mfma_f32_16x16x32_bf16(al[m], bh[n], acc[m][n], 0, 0, 0);
            }
    }

    // Epilogue. C/D layout (m89-verified): col = lane&15, row = (lane>>4)*4+reg
#pragma unroll
    for (int m = 0; m < 4; m++) {
#pragma unroll
        for (int n = 0; n < 4; n++) {
            int gn = bn + wc * 64 + n * 16 + l15;
            float bv = (MODE == 1 || MODE == 2) ? bias[gn] : 0.0f;
#pragma unroll
            for (int j = 0; j < 4; j++) {
                int gm = bm + wr * 64 + m * 16 + loct * 4 + j;
                float v = acc[m][n][j];
                if (MODE == 1 || MODE == 2) v += bv;
                if (MODE == 2) v = gelu_exact(v);
                if (MODE == 3) {
                    int b = gm >> 10, s = gm & 1023;
                    int hh = gn >> 6, dk = gn & 63;
                    C[(((size_t)(b * Hc + hh) * Sc) + s) * DKc + dk] = v;
                } else {
                    C[(size_t)gm * Nd + gn] = v;
                }
            }
        }
    }
}

// ---------------------------------------------------------------------------
// fp32 VALU GEMM — retained as fallback for Wout when ws can't hold the
// converted copy. MODE 1: +bias.
// ---------------------------------------------------------------------------
template<int MODE>
__global__ __launch_bounds__(256) void gemm_k(const float* __restrict__ A,
                                              const float* __restrict__ Bm,
                                              const float* __restrict__ bias,
                                              float* __restrict__ C,
                                              int Kd, int Nd) {
    __shared__ float As[16][68];
    __shared__ float Bs[16][68];
    int tid = threadIdx.x;
    int bm = blockIdx.y * 64;
    int bn = blockIdx.x * 64;
    int tx = tid & 15;
    int ty = tid >> 4;
    float acc[4][4] = {};

    int arow = tid >> 2;
    int akq  = tid & 3;
    int bkrow = tid >> 4;
    int bn4   = tid & 15;

    const float* Aptr = A + (size_t)(bm + arow) * Kd + akq * 4;
    const float* Bptr = Bm + (size_t)bkrow * Nd + bn + bn4 * 4;

    for (int k0 = 0; k0 < Kd; k0 += 16) {
        float4 av = *(const float4*)(Aptr + k0);
        float4 bv = *(const float4*)(Bptr + (size_t)k0 * Nd);
        As[akq * 4 + 0][arow] = av.x;
        As[akq * 4 + 1][arow] = av.y;
        As[akq * 4 + 2][arow] = av.z;
        As[akq * 4 + 3][arow] = av.w;
        *(float4*)&Bs[bkrow][bn4 * 4] = bv;
        __syncthreads();
#pragma unroll
        for (int kk = 0; kk < 16; kk++) {
            float4 a4 = *(const float4*)&As[kk][ty * 4];
            float4 b4 = *(const float4*)&Bs[kk][tx * 4];
            acc[0][0] += a4.x * b4.x; acc[0][1] += a4.x * b4.y;
            acc[0][2] += a4.x * b4.z; acc[0][3] += a4.x * b4.w;
            acc[1][0] += a4.y * b4.x; acc[1][1] += a4.y * b4.y;
            acc[1][2] += a4.y * b4.z; acc[1][3] += a4.y * b4.w;
            acc[2][0] += a4.z * b4.x; acc[2][1] += a4.z * b4.y;
            acc[2][2] += a4.z * b4.z; acc[2][3] += a4.z * b4.w;
            acc[3][0] += a4.w * b4.x; acc[3][1] += a4.w * b4.y;
            acc[3][2] += a4.w * b4.z; acc[3][3] += a4.w * b4.w;
        }
        __syncthreads();
    }

#pragma unroll
    for (int i = 0; i < 4; i++) {
        int gm = bm + ty * 4 + i;
#pragma unroll
        for (int j = 0; j < 4; j++) {
            int gn = bn + tx * 4 + j;
            float v = acc[i][j];
            if (MODE == 1 || MODE == 2) v += bias[gn];
            if (MODE == 2) v = gelu_exact(v);
            C[(size_t)gm * Nd + gn] = v;
        }
    }
}

// ---------------------------------------------------------------------------
// Flash-style attention, fp32. One wave per 64-query tile (unchanged r2).
// ---------------------------------------------------------------------------
constexpr int QT = 64;
constexpr int KT = 32;

__global__ __launch_bounds__(64) void fattn_k(const float* __restrict__ Q,
                                              const float* __restrict__ K,
                                              const float* __restrict__ V,
                                              const int* __restrict__ x,
                                              float* __restrict__ ctx) {
    int qt = blockIdx.x;
    int bh = blockIdx.y;
    int b = bh >> 4;
    int hh = bh & 15;
    int tid = threadIdx.x;
    int q = qt * QT + tid;

    __shared__ float Ks[KT][64];
    __shared__ float Vs[KT][64];
    __shared__ int   xs[KT];

    const float* Kb = K + (size_t)bh * Sc * DKc;
    const float* Vb = V + (size_t)bh * Sc * DKc;

    float4 q4[16];
    const float* qp = Q + ((size_t)bh * Sc + q) * DKc;
#pragma unroll
    for (int i = 0; i < 16; i++) q4[i] = *(const float4*)(qp + 4 * i);

    float4 acc[16];
#pragma unroll
    for (int i = 0; i < 16; i++) acc[i] = make_float4(0.f, 0.f, 0.f, 0.f);
    float m = -INFINITY, l = 0.0f;

    int ktiles = (qt * QT + QT) / KT;
    for (int t = 0; t < ktiles; t++) {
        int k0 = t * KT;
        __syncthreads();
        for (int f = tid; f < KT * 16; f += 64) {
            int kr = f >> 4;
            int dc = (f & 15) * 4;
            *(float4*)&Ks[kr][dc] = *(const float4*)&Kb[(size_t)(k0 + kr) * DKc + dc];
            *(float4*)&Vs[kr][dc] = *(const float4*)&Vb[(size_t)(k0 + kr) * DKc + dc];
        }
        if (tid < KT) xs[tid] = x[b * Sc + k0 + tid];
        __syncthreads();

        float sc[KT];
#pragma unroll
        for (int k = 0; k < KT; k++) {
            float4 s4 = make_float4(0.f, 0.f, 0.f, 0.f);
#pragma unroll
            for (int i = 0; i < 16; i++) {
                float4 kv = *(const float4*)&Ks[k][4 * i];
                s4.x += q4[i].x * kv.x;
                s4.y += q4[i].y * kv.y;
                s4.z += q4[i].z * kv.z;
                s4.w += q4[i].w * kv.w;
            }
            float s = (s4.x + s4.y) + (s4.z + s4.w);
            bool valid = ((k0 + k) <= q) && (xs[k] != 0);
            sc[k] = valid ? s * 0.125f : -INFINITY;
        }

        float tm = sc[0];
#pragma unroll
        for (int k = 1; k < KT; k++) tm = fmaxf(tm, sc[k]);
        float mnew = fmaxf(m, tm);
        float corr = __expf(m - mnew);
        l *= corr;
#pragma unroll
        for (int i = 0; i < 16; i++) {
            acc[i].x *= corr; acc[i].y *= corr;
            acc[i].z *= corr; acc[i].w *= corr;
        }
        m = mnew;

#pragma unroll
        for (int k = 0; k < KT; k++) {
            float p = __expf(sc[k] - m);
            l += p;
#pragma unroll
            for (int i = 0; i < 16; i++) {
                float4 vv = *(const float4*)&Vs[k][4 * i];
                acc[i].x += p * vv.x;
                acc[i].y += p * vv.y;
                acc[i].z += p * vv.z;
                acc[i].w += p * vv.w;
            }
        }
    }

    float inv = 1.0f / l;
    float* op = ctx + ((size_t)b * Sc + q) * Dc + hh * 64;
#pragma unroll
    for (int i = 0; i < 16; i++) {
        float4 o;
        o.x = acc[i].x * inv; o.y = acc[i].y * inv;
        o.z = acc[i].z * inv; o.w = acc[i].w * inv;
        *(float4*)(op + 4 * i) = o;
    }
}

// ---------------------------------------------------------------------------
// Residual add + LayerNorm over D=1024.
// ---------------------------------------------------------------------------
__global__ __launch_bounds__(256) void lnadd_k(const float* x, const float* r,
                                               const float* __restrict__ g,
                                               const float* __restrict__ bb,
                                               float* out) {
    int row = blockIdx.x, tid = threadIdx.x;
    int lane = tid & 63, wid = tid >> 6;
    __shared__ float red[8];
    size_t base = (size_t)row * Dc + tid * 4;
    float4 xv = *(const float4*)(x + base);
    float4 rv = *(const float4*)(r + base);
    float v0 = xv.x + rv.x, v1 = xv.y + rv.y, v2 = xv.z + rv.z, v3 = xv.w + rv.w;
    float sum = v0 + v1 + v2 + v3;
    float sq = v0 * v0 + v1 * v1 + v2 * v2 + v3 * v3;
    for (int off = 32; off; off >>= 1) {
        sum += __shfl_down(sum, off);
        sq  += __shfl_down(sq, off);
    }
    if (lane == 0) { red[wid] = sum; red[4 + wid] = sq; }
    __syncthreads();
    if (tid == 0) {
        red[0] = red[0] + red[1] + red[2] + red[3];
        red[4] = red[4] + red[5] + red[6] + red[7];
    }
    __syncthreads();
    float mu = red[0] * (1.0f / Dc);
    float var = red[4] * (1.0f / Dc) - mu * mu;
    float rs = rsqrtf(var + EPSc);
    int d = tid * 4;
    float4 gv = *(const float4*)(g + d);
    float4 bv = *(const float4*)(bb + d);
    float4 o;
    o.x = (v0 - mu) * rs * gv.x + bv.x;
    o.y = (v1 - mu) * rs * gv.y + bv.y;
    o.z = (v2 - mu) * rs * gv.z + bv.z;
    o.w = (v3 - mu) * rs * gv.w + bv.w;
    *(float4*)(out + base) = o;
}

// ---------------------------------------------------------------------------
extern "C" void kernel_launch(void* const* d_in, const int* in_sizes, int n_in,
                              void* d_out, int out_size, void* d_ws, size_t ws_size,
                              hipStream_t stream) {
    const int*   x     = (const int*)d_in[0];
    const float* emb   = (const float*)d_in[1];
    const float* Wq    = (const float*)d_in[2];
    const float* Wk    = (const float*)d_in[3];
    const float* Wv    = (const float*)d_in[4];
    const float* Wo    = (const float*)d_in[5];
    const float* bo    = (const float*)d_in[6];
    const float* ln1g  = (const float*)d_in[7];
    const float* ln1b  = (const float*)d_in[8];
    const float* ln2g  = (const float*)d_in[9];
    const float* ln2b  = (const float*)d_in[10];
    const float* W1    = (const float*)d_in[11];
    const float* b1    = (const float*)d_in[12];
    const float* W2    = (const float*)d_in[13];
    const float* b2    = (const float*)d_in[14];
    const float* Wout  = (const float*)d_in[15];
    const float* bout  = (const float*)d_in[16];
    float* out = (float*)d_out;
    float* ws = (float*)d_ws;

    const size_t MD = (size_t)Mc * Dc;   // 4M floats
    float* h    = ws;
    float* q    = ws + 1 * MD;
    float* k    = ws + 2 * MD;
    float* v    = ws + 3 * MD;
    float* ctx  = ws + 4 * MD;
    float* tmp  = ws + 5 * MD;
    float* ff1  = q;                     // reuses q..ctx span (16M floats)

    // Converted-weight scratch. Layer weights live in `out` (consumed before
    // the final GEMM writes logits). 192 MB < 524 MB output buffer.
    const size_t DD = (size_t)Dc * Dc;   // 1M elements
    const size_t DF = (size_t)Dc * Fc;   // 4M elements
    const size_t PL = 8 * DD + 4 * DF;   // per-layer ushorts (48 MB)
    ushort* conv = (ushort*)out;

    // Converted Wout goes after the fp32 buffers in ws, if it fits.
    const size_t used  = 6 * MD * sizeof(float);
    const size_t woutE = (size_t)Dc * Vc;
    bool wout_mfma = ws_size >= used + 2 * woutE * sizeof(ushort);
    ushort* woc_h = (ushort*)((char*)ws + used);
    ushort* woc_l = woc_h + woutE;

    embed_k<<<Mc, 256, 0, stream>>>(x, emb, h);

    // Pre-convert all weights to bf16 hi/lo, [n][k] layout.
    for (int l = 0; l < Lc; l++) {
        ushort* base = conv + (size_t)l * PL;
        wconv_k<<<dim3(16, 16), 256, 0, stream>>>(Wq + (size_t)l * DD, base + 0 * DD, base + 1 * DD, Dc, Dc);
        wconv_k<<<dim3(16, 16), 256, 0, stream>>>(Wk + (size_t)l * DD, base + 2 * DD, base + 3 * DD, Dc, Dc);
        wconv_k<<<dim3(16, 16), 256, 0, stream>>>(Wv + (size_t)l * DD, base + 4 * DD, base + 5 * DD, Dc, Dc);
        wconv_k<<<dim3(16, 16), 256, 0, stream>>>(Wo + (size_t)l * DD, base + 6 * DD, base + 7 * DD, Dc, Dc);
        wconv_k<<<dim3(64, 16), 256, 0, stream>>>(W1 + (size_t)l * DF, base + 8 * DD, base + 8 * DD + DF, Dc, Fc);
        wconv_k<<<dim3(16, 64), 256, 0, stream>>>(W2 + (size_t)l * DF, base + 8 * DD + 2 * DF, base + 8 * DD + 3 * DF, Fc, Dc);
    }
    if (wout_mfma)
        wconv_k<<<dim3(Vc / 64, 16), 256, 0, stream>>>(Wout, woc_h, woc_l, Dc, Vc);

    dim3 g1(Dc / 128, Mc / 128);    // (8, 32)
    dim3 gF(Fc / 128, Mc / 128);    // (32, 32)
    dim3 gV(Vc / 128, Mc / 128);    // (250, 32)

    for (int l = 0; l < Lc; l++) {
        ushort* base = conv + (size_t)l * PL;

        mgemm_k<3><<<g1, 256, 0, stream>>>(h, base + 0 * DD, base + 1 * DD, nullptr, q, Dc, Dc);
        mgemm_k<3><<<g1, 256, 0, stream>>>(h, base + 2 * DD, base + 3 * DD, nullptr, k, Dc, Dc);
        mgemm_k<3><<<g1, 256, 0, stream>>>(h, base + 4 * DD, base + 5 * DD, nullptr, v, Dc, Dc);

        fattn_k<<<dim3(Sc / QT, Bc * Hc), QT, 0, stream>>>(q, k, v, x, ctx);

        mgemm_k<1><<<g1, 256, 0, stream>>>(ctx, base + 6 * DD, base + 7 * DD, bo + l * Dc, tmp, Dc, Dc);
        lnadd_k<<<Mc, 256, 0, stream>>>(h, tmp, ln1g + l * Dc, ln1b + l * Dc, h);

        mgemm_k<2><<<gF, 256, 0, stream>>>(h, base + 8 * DD, base + 8 * DD + DF, b1 + l * Fc, ff1, Dc, Fc);
        mgemm_k<1><<<g1, 256, 0, stream>>>(ff1, base + 8 * DD + 2 * DF, base + 8 * DD + 3 * DF, b2 + l * Dc, tmp, Fc, Dc);
        lnadd_k<<<Mc, 256, 0, stream>>>(h, tmp, ln2g + l * Dc, ln2b + l * Dc, h);
    }

    if (wout_mfma)
        mgemm_k<1><<<gV, 256, 0, stream>>>(h, woc_h, woc_l, bout, out, Dc, Vc);
    else
        gemm_k<1><<<dim3(Vc / 64, Mc / 64), 256, 0, stream>>>(h, Wout, bout, out, Dc, Vc);
}